// Round 3
// baseline (666.165 us; speedup 1.0000x reference)
//
#include <hip/hip_runtime.h>
#include <hip/hip_bf16.h>

typedef __attribute__((ext_vector_type(8))) short short8;
typedef __attribute__((ext_vector_type(4))) float f32x4;

#define B_    8
#define N_    4097
#define C_    768
#define M_TOT (B_*N_)      /* 32776 */
#define K3    (3*C_)       /* 2304  */
#define CHUNKS 16
#define NSTEP 24           /* 768/32 K-steps */

__device__ __forceinline__ float bf2f(unsigned short u) {
  union { unsigned int i; float f; } x; x.i = ((unsigned int)u) << 16; return x.f;
}
__device__ __forceinline__ unsigned short f2bf(float f) {
  union { float f; unsigned int i; } x; x.f = f;
  unsigned int i = x.i + 0x7fffu + ((x.i >> 16) & 1u);
  return (unsigned short)(i >> 16);
}
__device__ __forceinline__ void gload16(const void* g, void* l) {
  __builtin_amdgcn_global_load_lds(
      (const __attribute__((address_space(1))) void*)g,
      (__attribute__((address_space(3))) void*)l, 16, 0, 0);
}

// ---------------- fp32 -> bf16 convert ----------------
__global__ __launch_bounds__(256) void cvt_kernel(const float* __restrict__ in,
                                                  unsigned short* __restrict__ out,
                                                  long n4) {
  long i = (long)blockIdx.x * blockDim.x + threadIdx.x;
  long stride = (long)gridDim.x * blockDim.x;
  for (; i < n4; i += stride) {
    float4 v = ((const float4*)in)[i];
    ushort4 o;
    o.x = f2bf(v.x); o.y = f2bf(v.y); o.z = f2bf(v.z); o.w = f2bf(v.w);
    ((ushort4*)out)[i] = o;
  }
}

// ============ GEMM1: qkv = x @ qkv_w^T (256x256 tile, ring-4, fused bias+RoPE) ============
__global__ __launch_bounds__(512, 2) void gemm_qkv_rope(
    const unsigned short* __restrict__ A,    // [32776,768]
    const unsigned short* __restrict__ Bw,   // [2304,768]
    const float* __restrict__ rope,          // [4096,128]
    const float* __restrict__ qb,
    const float* __restrict__ vb,
    unsigned short* __restrict__ qkv)        // planes [3][32776][768]
{
  __shared__ __align__(16) unsigned short L[65536];   // 4 slots x 32KB
  const int tid  = threadIdx.x;
  const int wave = tid >> 6, lane = tid & 63;
  const int lr = lane & 15, lk = lane >> 4;
  const int wm = wave >> 2, wn = wave & 3;

  // bijective XCD swizzle: nwg=1161, q=145, r=1
  const int o = blockIdx.x;
  const int xcd = o & 7, loc = o >> 3;
  const int tile = (xcd < 1 ? xcd*146 : 146 + (xcd-1)*145) + loc;
  const int m0 = (tile / 9) * 256;
  const int n0 = (tile % 9) * 256;

  // ---- staging precompute (per thread, 4 x 16B per step) ----
  const int srow = tid >> 2;                 // 0..127
  const int sslot = tid & 3;
  const int ssw = (srow + (srow >> 2)) & 3;  // same for srow and srow+128
  const int scol = ((sslot ^ ssw) << 3);     // source k-element within 32
  const int ar1 = min(m0 + srow,       M_TOT-1);
  const int ar2 = min(m0 + srow + 128, M_TOT-1);
  const unsigned short* gA1 = A  + (long)ar1*768 + scol;
  const unsigned short* gA2 = A  + (long)ar2*768 + scol;
  const unsigned short* gB1 = Bw + (long)(n0 + srow)*768 + scol;
  const unsigned short* gB2 = Bw + (long)(n0 + srow + 128)*768 + scol;
  const int dA1 = wave*1024, dA2 = 8192 + wave*1024;
  const int dB1 = 16384 + wave*1024, dB2 = 24576 + wave*1024;

  // ---- fragment-read precompute ----
  const int sxor = (lr + (lr >> 2)) & 3;
  const int abase = (wm*128 + lr)*64 + ((lk ^ sxor) << 4);
  const int bbase = 16384 + (wn*64 + lr)*64 + ((lk ^ sxor) << 4);

  f32x4 acc[8][4];
#pragma unroll
  for (int i = 0; i < 8; ++i)
#pragma unroll
    for (int j = 0; j < 4; ++j) acc[i][j] = (f32x4){0.f,0.f,0.f,0.f};

#define STAGE1(s) { char* sb = (char*)L + ((s)&3)*32768; \
    gload16(gA1 + (s)*32, sb + dA1); gload16(gA2 + (s)*32, sb + dA2); \
    gload16(gB1 + (s)*32, sb + dB1); gload16(gB2 + (s)*32, sb + dB2); }

#define COMPUTE1(slot) { const char* sb = (const char*)L + (slot)*32768; \
    short8 bf[4]; \
    _Pragma("unroll") for (int ni = 0; ni < 4; ++ni) \
      bf[ni] = *(const short8*)(sb + bbase + ni*1024); \
    __builtin_amdgcn_s_setprio(1); \
    _Pragma("unroll") for (int mi = 0; mi < 8; ++mi) { \
      short8 af = *(const short8*)(sb + abase + mi*1024); \
      _Pragma("unroll") for (int ni = 0; ni < 4; ++ni) \
        acc[mi][ni] = __builtin_amdgcn_mfma_f32_16x16x32_bf16(af, bf[ni], acc[mi][ni], 0, 0, 0); \
    } \
    __builtin_amdgcn_s_setprio(0); }

  STAGE1(0) STAGE1(1) STAGE1(2)
  for (int t = 0; t < NSTEP-3; ++t) {
    asm volatile("s_waitcnt vmcnt(8)" ::: "memory");
    __builtin_amdgcn_s_barrier();
    __builtin_amdgcn_sched_barrier(0);
    STAGE1(t+3)
    COMPUTE1(t & 3)
  }
  asm volatile("s_waitcnt vmcnt(8)" ::: "memory");
  __builtin_amdgcn_s_barrier();
  __builtin_amdgcn_sched_barrier(0);
  COMPUTE1((NSTEP-3) & 3)
  asm volatile("s_waitcnt vmcnt(4)" ::: "memory");
  __builtin_amdgcn_s_barrier();
  __builtin_amdgcn_sched_barrier(0);
  COMPUTE1((NSTEP-2) & 3)
  asm volatile("s_waitcnt vmcnt(0)" ::: "memory");
  __builtin_amdgcn_s_barrier();
  __builtin_amdgcn_sched_barrier(0);
  COMPUTE1((NSTEP-1) & 3)

  // ---- epilogue: bias + RoPE + bf16 store to planes ----
  const int which = n0 / 768;
  unsigned short* plane = qkv + (long)which*M_TOT*768;
#pragma unroll
  for (int mi = 0; mi < 8; ++mi) {
#pragma unroll
    for (int ni = 0; ni < 4; ++ni) {
      const int gc = n0 + wn*64 + ni*16 + lr;
      const int within = gc - which*768;
      const int d = within & 63;
      float bias = 0.f;
      if (which == 0) bias = qb[within];
      else if (which == 2) bias = vb[within];
#pragma unroll
      for (int r = 0; r < 4; ++r) {
        const int gm = m0 + wm*128 + mi*16 + lk*4 + r;
        float v = acc[mi][ni][r] + bias;
        float pair = __shfl_xor(v, 1);
        float vo = v;
        if (which < 2) {
          const int ntok = gm % 4097;
          if (ntok > 0 && gm < M_TOT) {
            const float* rp = rope + (long)(ntok - 1)*128 + d;
            const float s = rp[0], c = rp[64];
            const float rot = (d & 1) ? pair : -pair;
            vo = v*c + rot*s;
          }
        }
        if (gm < M_TOT) plane[(long)gm*768 + within] = f2bf(vo);
      }
    }
  }
}

// ---------------- kv partials: kv[b,h] = K^T V over an N-chunk ----------------
__global__ __launch_bounds__(256) void kv_partial_kernel(
    const unsigned short* __restrict__ qkv, float* __restrict__ part)
{
  const int bh = blockIdx.y;
  const int b = bh / 12, h = bh % 12;
  const int chunk = blockIdx.x;
  const int per = (N_ + CHUNKS - 1) / CHUNKS;
  const int nst = chunk * per;
  const int nen = min(nst + per, N_);
  const unsigned short* Kpl = qkv + (long)M_TOT*768 + ((long)b*N_)*768 + h*64;
  const unsigned short* Vpl = qkv + (long)2*M_TOT*768 + ((long)b*N_)*768 + h*64;
  __shared__ unsigned short Kl[32*64];
  __shared__ unsigned short Vl[32*64];
  const int t = threadIdx.x;
  const int ty = t >> 4, tx = t & 15;
  const int lrow = t >> 3, lpc = t & 7;
  float acc[4][4] = {};
  for (int nb = nst; nb < nen; nb += 32) {
    const int cnt = min(32, nen - nb);
    __syncthreads();
    if (lrow < cnt) {
      *(uint4*)(Kl + lrow*64 + lpc*8) = *(const uint4*)(Kpl + (long)(nb + lrow)*768 + lpc*8);
      *(uint4*)(Vl + lrow*64 + lpc*8) = *(const uint4*)(Vpl + (long)(nb + lrow)*768 + lpc*8);
    }
    __syncthreads();
#pragma unroll 2
    for (int i = 0; i < cnt; ++i) {
      const ushort4 ku = *(const ushort4*)(Kl + i*64 + ty*4);
      const ushort4 vu = *(const ushort4*)(Vl + i*64 + tx*4);
      float kf[4] = {bf2f(ku.x), bf2f(ku.y), bf2f(ku.z), bf2f(ku.w)};
      float vf[4] = {bf2f(vu.x), bf2f(vu.y), bf2f(vu.z), bf2f(vu.w)};
#pragma unroll
      for (int a = 0; a < 4; ++a)
#pragma unroll
        for (int e = 0; e < 4; ++e) acc[a][e] += kf[a]*vf[e];
    }
  }
  float* dst = part + ((long)chunk*96 + bh)*4096 + (ty*4)*64 + tx*4;
#pragma unroll
  for (int a = 0; a < 4; ++a)
#pragma unroll
    for (int e = 0; e < 4; ++e) dst[a*64 + e] = acc[a][e];
}

__global__ __launch_bounds__(256) void kv_reduce_kernel(const float* __restrict__ part,
                                                        float* __restrict__ kvf) {
  const int i = blockIdx.x*256 + threadIdx.x;
  float s = 0.f;
#pragma unroll
  for (int c = 0; c < CHUNKS; ++c) s += part[(long)c*96*4096 + i];
  kvf[i] = s;
}

// ---- McombT[b][c][h*64+d] = sum_e kv[b,h,d,e]*proj_w[c,h*64+e] / (hd*N) ----
// grid: 768 blocks = b(8) x h(12) x dgroup(8); block covers all 768 c, 8 d.
__global__ __launch_bounds__(256) void mcomb_kernel(const float* __restrict__ kvf,
                                                    const float* __restrict__ pw,
                                                    unsigned short* __restrict__ McT) {
  const int blk = blockIdx.x;
  const int dg = blk & 7;
  const int h  = (blk >> 3) % 12;
  const int b  = blk / 96;
  __shared__ float kvs[8][64];
  const int t = threadIdx.x;
  if (t < 128) {
    const int d = t >> 4, e4 = t & 15;
    ((float4*)kvs[d])[e4] =
      ((const float4*)(kvf + (((long)(b*12 + h)*64 + dg*8 + d) << 6)))[e4];
  }
  __syncthreads();
  const float scale = (float)(1.0/(64.0*4097.0));
#pragma unroll
  for (int ci = 0; ci < 3; ++ci) {
    const int c = t + ci*256;
    const float4* pwp = (const float4*)(pw + (long)c*768 + h*64);
    float4 pv[16];
#pragma unroll
    for (int i = 0; i < 16; ++i) pv[i] = pwp[i];
#pragma unroll
    for (int d = 0; d < 8; ++d) {
      float s = 0.f;
#pragma unroll
      for (int e4 = 0; e4 < 16; ++e4) {
        const float4 kq = ((const float4*)kvs[d])[e4];
        s += pv[e4].x*kq.x + pv[e4].y*kq.y + pv[e4].z*kq.z + pv[e4].w*kq.w;
      }
      McT[((long)b*768 + c)*768 + h*64 + dg*8 + d] = f2bf(s * scale);
    }
  }
}

// ============ GEMM2: out[b] = Q[b] @ McT[b]^T + proj_b (256x256 tile, ring-4) ============
__global__ __launch_bounds__(512, 2) void gemm_final(
    const unsigned short* __restrict__ qkv,   // q plane
    const unsigned short* __restrict__ McT,   // [8,768,768]
    const float* __restrict__ pb,
    float* __restrict__ out)
{
  __shared__ __align__(16) unsigned short L[65536];
  const int tid  = threadIdx.x;
  const int wave = tid >> 6, lane = tid & 63;
  const int lr = lane & 15, lk = lane >> 4;
  const int wm = wave >> 2, wn = wave & 3;

  // XCD swizzle: nwg=408 = 8*51
  const int o = blockIdx.x;
  const int xcd = o & 7, loc = o >> 3;
  const int tile = xcd*51 + loc;
  const int b  = tile / 51;     // == xcd
  const int rem = tile % 51;
  const int mt = rem / 3, nt = rem % 3;
  const int m0 = mt * 256;      // token tile start (within batch)
  const int c0 = nt * 256;

  const int srow = tid >> 2;
  const int sslot = tid & 3;
  const int ssw = (srow + (srow >> 2)) & 3;
  const int scol = ((sslot ^ ssw) << 3);
  const int tr1 = min(m0 + srow,       N_-1);
  const int tr2 = min(m0 + srow + 128, N_-1);
  const unsigned short* gA1 = qkv + ((long)b*N_ + tr1)*768 + scol;
  const unsigned short* gA2 = qkv + ((long)b*N_ + tr2)*768 + scol;
  const unsigned short* Bb = McT + (long)b*768*768;
  const unsigned short* gB1 = Bb + (long)(c0 + srow)*768 + scol;
  const unsigned short* gB2 = Bb + (long)(c0 + srow + 128)*768 + scol;
  const int dA1 = wave*1024, dA2 = 8192 + wave*1024;
  const int dB1 = 16384 + wave*1024, dB2 = 24576 + wave*1024;

  const int sxor = (lr + (lr >> 2)) & 3;
  const int abase = (wm*128 + lr)*64 + ((lk ^ sxor) << 4);
  const int bbase = 16384 + (wn*64 + lr)*64 + ((lk ^ sxor) << 4);

  f32x4 acc[8][4];
#pragma unroll
  for (int i = 0; i < 8; ++i)
#pragma unroll
    for (int j = 0; j < 4; ++j) acc[i][j] = (f32x4){0.f,0.f,0.f,0.f};

#define STAGE2(s) { char* sb = (char*)L + ((s)&3)*32768; \
    gload16(gA1 + (s)*32, sb + dA1); gload16(gA2 + (s)*32, sb + dA2); \
    gload16(gB1 + (s)*32, sb + dB1); gload16(gB2 + (s)*32, sb + dB2); }

  STAGE2(0) STAGE2(1) STAGE2(2)
  for (int t = 0; t < NSTEP-3; ++t) {
    asm volatile("s_waitcnt vmcnt(8)" ::: "memory");
    __builtin_amdgcn_s_barrier();
    __builtin_amdgcn_sched_barrier(0);
    STAGE2(t+3)
    COMPUTE1(t & 3)
  }
  asm volatile("s_waitcnt vmcnt(8)" ::: "memory");
  __builtin_amdgcn_s_barrier();
  __builtin_amdgcn_sched_barrier(0);
  COMPUTE1((NSTEP-3) & 3)
  asm volatile("s_waitcnt vmcnt(4)" ::: "memory");
  __builtin_amdgcn_s_barrier();
  __builtin_amdgcn_sched_barrier(0);
  COMPUTE1((NSTEP-2) & 3)
  asm volatile("s_waitcnt vmcnt(0)" ::: "memory");
  __builtin_amdgcn_s_barrier();
  __builtin_amdgcn_sched_barrier(0);
  COMPUTE1((NSTEP-1) & 3)

#pragma unroll
  for (int mi = 0; mi < 8; ++mi) {
#pragma unroll
    for (int ni = 0; ni < 4; ++ni) {
      const int gc = c0 + wn*64 + ni*16 + lr;
      const float bias = pb[gc];
#pragma unroll
      for (int r = 0; r < 4; ++r) {
        const int tok = m0 + wm*128 + mi*16 + lk*4 + r;
        if (tok < N_)
          out[((long)b*N_ + tok)*768 + gc] = acc[mi][ni][r] + bias;
      }
    }
  }
}

extern "C" void kernel_launch(void* const* d_in, const int* in_sizes, int n_in,
                              void* d_out, int out_size, void* d_ws, size_t ws_size,
                              hipStream_t stream) {
  const float* x      = (const float*)d_in[0];
  const float* rope   = (const float*)d_in[1];
  const float* qkv_w  = (const float*)d_in[2];
  const float* q_bias = (const float*)d_in[3];
  const float* v_bias = (const float*)d_in[4];
  const float* proj_w = (const float*)d_in[5];
  const float* proj_b = (const float*)d_in[6];
  float* out = (float*)d_out;

  char* w0 = (char*)d_ws;
  unsigned short* x_bf  = (unsigned short*)w0;
  unsigned short* wq_bf = (unsigned short*)(w0 + 50343936);
  unsigned short* qkv   = (unsigned short*)(w0 + 50343936 + 3538944);
  float*          part  = (float*)w0;                     // aliases x_bf (dead)
  float*          kvf   = (float*)(w0 + 25165824);
  unsigned short* McT   = (unsigned short*)(w0 + 25165824 + 1572864);

  cvt_kernel<<<2048, 256, 0, stream>>>(x, x_bf, (long)M_TOT*768/4);
  cvt_kernel<<<1728, 256, 0, stream>>>(qkv_w, wq_bf, (long)K3*768/4);

  gemm_qkv_rope<<<1161, 512, 0, stream>>>(x_bf, wq_bf, rope, q_bias, v_bias, qkv);

  kv_partial_kernel<<<dim3(CHUNKS, 96), 256, 0, stream>>>(qkv, part);
  kv_reduce_kernel<<<1536, 256, 0, stream>>>(part, kvf);
  mcomb_kernel<<<768, 256, 0, stream>>>(kvf, proj_w, McT);

  gemm_final<<<408, 512, 0, stream>>>(qkv, McT, proj_b, out);
}

// Round 4
// 652.772 us; speedup vs baseline: 1.0205x; 1.0205x over previous
//
#include <hip/hip_runtime.h>
#include <hip/hip_bf16.h>

typedef __attribute__((ext_vector_type(8))) short short8;
typedef __attribute__((ext_vector_type(4))) float f32x4;

#define B_    8
#define N_    4097
#define C_    768
#define M_TOT (B_*N_)      /* 32776 */
#define K3    (3*C_)       /* 2304  */
#define CHUNKS 16
#define NSTEP 24           /* 768/32 K-steps */

__device__ __forceinline__ float bf2f(unsigned short u) {
  union { unsigned int i; float f; } x; x.i = ((unsigned int)u) << 16; return x.f;
}
__device__ __forceinline__ unsigned short f2bf(float f) {
  union { float f; unsigned int i; } x; x.f = f;
  unsigned int i = x.i + 0x7fffu + ((x.i >> 16) & 1u);
  return (unsigned short)(i >> 16);
}
__device__ __forceinline__ void gload16(const void* g, void* l) {
  __builtin_amdgcn_global_load_lds(
      (const __attribute__((address_space(1))) void*)g,
      (__attribute__((address_space(3))) void*)l, 16, 0, 0);
}

// ---------------- fp32 -> bf16 convert ----------------
__global__ __launch_bounds__(256) void cvt_kernel(const float* __restrict__ in,
                                                  unsigned short* __restrict__ out,
                                                  long n4) {
  long i = (long)blockIdx.x * blockDim.x + threadIdx.x;
  long stride = (long)gridDim.x * blockDim.x;
  for (; i < n4; i += stride) {
    float4 v = ((const float4*)in)[i];
    ushort4 o;
    o.x = f2bf(v.x); o.y = f2bf(v.y); o.z = f2bf(v.z); o.w = f2bf(v.w);
    ((ushort4*)out)[i] = o;
  }
}

// ============ GEMM1: qkv = x @ qkv_w^T  (256x256, ring-4 BK=32, 2 phases/step) ============
__global__ __launch_bounds__(512, 2) void gemm_qkv_rope(
    const unsigned short* __restrict__ A,    // [32776,768]
    const unsigned short* __restrict__ Bw,   // [2304,768]
    const float* __restrict__ rope,          // [4096,128]
    const float* __restrict__ qb,
    const float* __restrict__ vb,
    unsigned short* __restrict__ qkv)        // planes [3][32776][768]
{
  __shared__ __align__(16) unsigned short L[4*16384];   // 4 slots x 32KB
  const int tid  = threadIdx.x;
  const int wave = tid >> 6, lane = tid & 63;
  const int lr = lane & 15, lk = lane >> 4;
  const int wm = wave >> 2, wn = wave & 3;

  // bijective XCD swizzle: nwg=1161, q=145, r=1
  const int o = blockIdx.x;
  const int xcd = o & 7, loc = o >> 3;
  const int tile = (xcd < 1 ? xcd*146 : 146 + (xcd-1)*145) + loc;
  const int m0 = (tile / 9) * 256;
  const int n0 = (tile % 9) * 256;

  // ---- staging precompute: thread covers (srow, sslot); swizzled source col ----
  const int srow = tid >> 2;                 // 0..127
  const int sslot = tid & 3;
  const int ssw = (srow + (srow >> 2)) & 3;  // same for srow+128, +16-multiples
  const int scol = ((sslot ^ ssw) << 3);     // k-element offset within 32
  const int ar1 = min(m0 + srow,       M_TOT-1);
  const int ar2 = min(m0 + srow + 128, M_TOT-1);
  const unsigned short* gA1 = A  + (long)ar1*768 + scol;
  const unsigned short* gA2 = A  + (long)ar2*768 + scol;
  const unsigned short* gB1 = Bw + (long)(n0 + srow)*768 + scol;
  const unsigned short* gB2 = Bw + (long)(n0 + srow + 128)*768 + scol;
  const int dA1 = wave*1024, dA2 = 8192 + wave*1024;
  const int dB1 = 16384 + wave*1024, dB2 = 24576 + wave*1024;

  // ---- fragment-read precompute (unswizzle on read) ----
  const int sxor = (lr + (lr >> 2)) & 3;
  const int abase = (wm*128 + lr)*64 + ((lk ^ sxor) << 4);
  const int bbase = 16384 + (wn*64 + lr)*64 + ((lk ^ sxor) << 4);

  f32x4 acc[8][4];
#pragma unroll
  for (int i = 0; i < 8; ++i)
#pragma unroll
    for (int j = 0; j < 4; ++j) acc[i][j] = (f32x4){0.f,0.f,0.f,0.f};

  // Phase A: read B-frags(4) + A-frags mi0..3(4); stage A-halves of t+3; 16 MFMA.
#define PHASE_A(t, DO_STAGE) { \
    const char* sb = (const char*)L + ((t)&3)*32768; \
    short8 afA[4]; \
    _Pragma("unroll") for (int ni = 0; ni < 4; ++ni) \
      bf[ni] = *(const short8*)(sb + bbase + ni*1024); \
    _Pragma("unroll") for (int mi = 0; mi < 4; ++mi) \
      afA[mi] = *(const short8*)(sb + abase + mi*1024); \
    if (DO_STAGE) { char* db = (char*)L + (((t)+3)&3)*32768; \
      gload16(gA1 + ((t)+3)*32, db + dA1); \
      gload16(gA2 + ((t)+3)*32, db + dA2); } \
    __builtin_amdgcn_s_barrier(); \
    asm volatile("s_waitcnt lgkmcnt(0)" ::: "memory"); \
    __builtin_amdgcn_s_setprio(1); \
    _Pragma("unroll") for (int mi = 0; mi < 4; ++mi) \
      _Pragma("unroll") for (int ni = 0; ni < 4; ++ni) \
        acc[mi][ni] = __builtin_amdgcn_mfma_f32_16x16x32_bf16(afA[mi], bf[ni], acc[mi][ni], 0, 0, 0); \
    __builtin_amdgcn_s_setprio(0); \
    __builtin_amdgcn_s_barrier(); \
    __builtin_amdgcn_sched_barrier(0); \
  }

  // Phase B: read A-frags mi4..7(4); stage B-halves of t+3; counted vmcnt; 16 MFMA.
#define PHASE_B(t, DO_STAGE, VMSTMT) { \
    const char* sb = (const char*)L + ((t)&3)*32768; \
    short8 afB[4]; \
    _Pragma("unroll") for (int mi = 0; mi < 4; ++mi) \
      afB[mi] = *(const short8*)(sb + abase + (4+mi)*1024); \
    if (DO_STAGE) { char* db = (char*)L + (((t)+3)&3)*32768; \
      gload16(gB1 + ((t)+3)*32, db + dB1); \
      gload16(gB2 + ((t)+3)*32, db + dB2); } \
    VMSTMT; \
    __builtin_amdgcn_s_barrier(); \
    asm volatile("s_waitcnt lgkmcnt(0)" ::: "memory"); \
    __builtin_amdgcn_s_setprio(1); \
    _Pragma("unroll") for (int mi = 0; mi < 4; ++mi) \
      _Pragma("unroll") for (int ni = 0; ni < 4; ++ni) \
        acc[4+mi][ni] = __builtin_amdgcn_mfma_f32_16x16x32_bf16(afB[mi], bf[ni], acc[4+mi][ni], 0, 0, 0); \
    __builtin_amdgcn_s_setprio(0); \
    __builtin_amdgcn_s_barrier(); \
    __builtin_amdgcn_sched_barrier(0); \
  }

  // prologue: fully stage slots 0,1,2 (groups in slot order for the ledger)
#pragma unroll
  for (int s = 0; s < 3; ++s) {
    char* db = (char*)L + s*32768;
    gload16(gA1 + s*32, db + dA1);
    gload16(gA2 + s*32, db + dA2);
    gload16(gB1 + s*32, db + dB1);
    gload16(gB2 + s*32, db + dB2);
  }
  asm volatile("s_waitcnt vmcnt(8)" ::: "memory");   // slot 0 landed
  __builtin_amdgcn_s_barrier();
  __builtin_amdgcn_sched_barrier(0);

  for (int t = 0; t < NSTEP-3; ++t) {                // t = 0..20
    short8 bf[4];
    PHASE_A(t, 1)
    PHASE_B(t, 1, asm volatile("s_waitcnt vmcnt(8)" ::: "memory"))
  }
  { short8 bf[4];
    PHASE_A(NSTEP-3, 0)
    PHASE_B(NSTEP-3, 0, asm volatile("s_waitcnt vmcnt(4)" ::: "memory")) }
  { short8 bf[4];
    PHASE_A(NSTEP-2, 0)
    PHASE_B(NSTEP-2, 0, asm volatile("s_waitcnt vmcnt(0)" ::: "memory")) }
  { short8 bf[4];
    PHASE_A(NSTEP-1, 0)
    PHASE_B(NSTEP-1, 0, ) }

  // ---- epilogue: bias + RoPE + bf16 store to planes ----
  const int which = n0 / 768;
  unsigned short* plane = qkv + (long)which*M_TOT*768;
#pragma unroll
  for (int mi = 0; mi < 8; ++mi) {
#pragma unroll
    for (int ni = 0; ni < 4; ++ni) {
      const int gc = n0 + wn*64 + ni*16 + lr;
      const int within = gc - which*768;
      const int d = within & 63;
      float bias = 0.f;
      if (which == 0) bias = qb[within];
      else if (which == 2) bias = vb[within];
#pragma unroll
      for (int r = 0; r < 4; ++r) {
        const int gm = m0 + wm*128 + mi*16 + lk*4 + r;
        float v = acc[mi][ni][r] + bias;
        float pair = __shfl_xor(v, 1);
        float vo = v;
        if (which < 2) {
          const int ntok = gm % 4097;
          if (ntok > 0 && gm < M_TOT) {
            const float* rp = rope + (long)(ntok - 1)*128 + d;
            const float s = rp[0], c = rp[64];
            const float rot = (d & 1) ? pair : -pair;
            vo = v*c + rot*s;
          }
        }
        if (gm < M_TOT) plane[(long)gm*768 + within] = f2bf(vo);
      }
    }
  }
}

// ---------------- kv partials: kv[b,h] = K^T V over an N-chunk ----------------
__global__ __launch_bounds__(256) void kv_partial_kernel(
    const unsigned short* __restrict__ qkv, float* __restrict__ part)
{
  const int bh = blockIdx.y;
  const int b = bh / 12, h = bh % 12;
  const int chunk = blockIdx.x;
  const int per = (N_ + CHUNKS - 1) / CHUNKS;
  const int nst = chunk * per;
  const int nen = min(nst + per, N_);
  const unsigned short* Kpl = qkv + (long)M_TOT*768 + ((long)b*N_)*768 + h*64;
  const unsigned short* Vpl = qkv + (long)2*M_TOT*768 + ((long)b*N_)*768 + h*64;
  __shared__ unsigned short Kl[32*64];
  __shared__ unsigned short Vl[32*64];
  const int t = threadIdx.x;
  const int ty = t >> 4, tx = t & 15;
  const int lrow = t >> 3, lpc = t & 7;
  float acc[4][4] = {};
  for (int nb = nst; nb < nen; nb += 32) {
    const int cnt = min(32, nen - nb);
    __syncthreads();
    if (lrow < cnt) {
      *(uint4*)(Kl + lrow*64 + lpc*8) = *(const uint4*)(Kpl + (long)(nb + lrow)*768 + lpc*8);
      *(uint4*)(Vl + lrow*64 + lpc*8) = *(const uint4*)(Vpl + (long)(nb + lrow)*768 + lpc*8);
    }
    __syncthreads();
#pragma unroll 2
    for (int i = 0; i < cnt; ++i) {
      const ushort4 ku = *(const ushort4*)(Kl + i*64 + ty*4);
      const ushort4 vu = *(const ushort4*)(Vl + i*64 + tx*4);
      float kf[4] = {bf2f(ku.x), bf2f(ku.y), bf2f(ku.z), bf2f(ku.w)};
      float vf[4] = {bf2f(vu.x), bf2f(vu.y), bf2f(vu.z), bf2f(vu.w)};
#pragma unroll
      for (int a = 0; a < 4; ++a)
#pragma unroll
        for (int e = 0; e < 4; ++e) acc[a][e] += kf[a]*vf[e];
    }
  }
  float* dst = part + ((long)chunk*96 + bh)*4096 + (ty*4)*64 + tx*4;
#pragma unroll
  for (int a = 0; a < 4; ++a)
#pragma unroll
    for (int e = 0; e < 4; ++e) dst[a*64 + e] = acc[a][e];
}

__global__ __launch_bounds__(256) void kv_reduce_kernel(const float* __restrict__ part,
                                                        float* __restrict__ kvf) {
  const int i = blockIdx.x*256 + threadIdx.x;
  float s = 0.f;
#pragma unroll
  for (int c = 0; c < CHUNKS; ++c) s += part[(long)c*96*4096 + i];
  kvf[i] = s;
}

// ---- McombT[b][c][h*64+d] = sum_e kv[b,h,d,e]*proj_w[c,h*64+e] / (hd*N) ----
__global__ __launch_bounds__(256) void mcomb_kernel(const float* __restrict__ kvf,
                                                    const float* __restrict__ pw,
                                                    unsigned short* __restrict__ McT) {
  const int blk = blockIdx.x;
  const int dg = blk & 7;
  const int h  = (blk >> 3) % 12;
  const int b  = blk / 96;
  __shared__ float kvs[8][64];
  const int t = threadIdx.x;
  if (t < 128) {
    const int d = t >> 4, e4 = t & 15;
    ((float4*)kvs[d])[e4] =
      ((const float4*)(kvf + (((long)(b*12 + h)*64 + dg*8 + d) << 6)))[e4];
  }
  __syncthreads();
  const float scale = (float)(1.0/(64.0*4097.0));
#pragma unroll
  for (int ci = 0; ci < 3; ++ci) {
    const int c = t + ci*256;
    const float4* pwp = (const float4*)(pw + (long)c*768 + h*64);
    float4 pv[16];
#pragma unroll
    for (int i = 0; i < 16; ++i) pv[i] = pwp[i];
#pragma unroll
    for (int d = 0; d < 8; ++d) {
      float s = 0.f;
#pragma unroll
      for (int e4 = 0; e4 < 16; ++e4) {
        const float4 kq = ((const float4*)kvs[d])[e4];
        s += pv[e4].x*kq.x + pv[e4].y*kq.y + pv[e4].z*kq.z + pv[e4].w*kq.w;
      }
      McT[((long)b*768 + c)*768 + h*64 + dg*8 + d] = f2bf(s * scale);
    }
  }
}

// ============ GEMM2: out[b] = Q[b] @ McT[b]^T + proj_b (128^2 tile, ring-3; R2) ============
__global__ __launch_bounds__(256) void gemm_final(
    const unsigned short* __restrict__ qkv,   // q plane = first M_TOT*768
    const unsigned short* __restrict__ McT,   // [8,768,768] bf16
    const float* __restrict__ pb,
    float* __restrict__ out)
{
  __shared__ unsigned short L2[3*8192];
  const int t    = threadIdx.x;
  const int wave = t >> 6, lane = t & 63;

  // bijective XCD swizzle: nwg=1584 = 8*198 (one batch per XCD)
  const int o   = blockIdx.x;
  const int xcd = o & 7, loc = o >> 3;
  const int tile = xcd*198 + loc;
  const int ct = tile % 6, yt = tile / 6;
  const int b = yt / 33, rt = yt % 33;
  const int n0 = rt * 128;     // token tile start
  const int c0 = ct * 128;     // output-channel tile start

  const int wr = wave >> 1, wc = wave & 1;
  const int lr = lane & 15, lk = lane >> 4;

  f32x4 acc[4][4];
#pragma unroll
  for (int i = 0; i < 4; ++i)
#pragma unroll
    for (int j = 0; j < 4; ++j) acc[i][j] = (f32x4){0.f,0.f,0.f,0.f};

  const int so0 = (wave*2 + 0) * 1024;
  const int so1 = (wave*2 + 1) * 1024;
  const int f0 = so0 + lane*16, f1 = so1 + lane*16;
  const int r0 = f0 >> 6, cb0 = f0 & 63;
  const int r1 = f1 >> 6, cb1 = f1 & 63;
  const int tk0 = min(n0 + r0, N_-1);
  const int tk1 = min(n0 + r1, N_-1);
  const unsigned short* ga0 = qkv + ((long)b*N_ + tk0)*768 + (cb0 >> 1);
  const unsigned short* ga1 = qkv + ((long)b*N_ + tk1)*768 + (cb1 >> 1);
  const unsigned short* Bb = McT + (long)b*768*768;
  const unsigned short* gb0 = Bb + (long)(c0 + r0)*768 + (cb0 >> 1);
  const unsigned short* gb1 = Bb + (long)(c0 + r1)*768 + (cb1 >> 1);

  auto STAGE = [&](int buf, int kk) {
    char* base = (char*)L2 + buf*16384;
    gload16(ga0 + kk, base + so0);
    gload16(ga1 + kk, base + so1);
    gload16(gb0 + kk, base + 8192 + so0);
    gload16(gb1 + kk, base + 8192 + so1);
  };
  auto COMPUTE = [&](int buf) {
    const unsigned short* Ab = L2 + buf*8192;
    const unsigned short* Bl = Ab + 4096;
    short8 af[4], bfr[4];
#pragma unroll
    for (int mi = 0; mi < 4; ++mi)
      af[mi] = *(const short8*)(Ab + (wr*64 + mi*16 + lr)*32 + lk*8);
#pragma unroll
    for (int ni = 0; ni < 4; ++ni)
      bfr[ni] = *(const short8*)(Bl + (wc*64 + ni*16 + lr)*32 + lk*8);
#pragma unroll
    for (int mi = 0; mi < 4; ++mi)
#pragma unroll
      for (int ni = 0; ni < 4; ++ni)
        acc[mi][ni] = __builtin_amdgcn_mfma_f32_16x16x32_bf16(af[mi], bfr[ni], acc[mi][ni], 0, 0, 0);
  };

  STAGE(0, 0);
  STAGE(1, 32);
  asm volatile("s_waitcnt vmcnt(4)" ::: "memory");
  __builtin_amdgcn_s_barrier();
  __builtin_amdgcn_sched_barrier(0);

  int cur = 0;
  for (int tt = 0; tt < NSTEP-2; ++tt) {
    int stg = cur + 2; if (stg >= 3) stg -= 3;
    STAGE(stg, (tt+2)*32);
    COMPUTE(cur);
    asm volatile("s_waitcnt vmcnt(4)" ::: "memory");
    __builtin_amdgcn_sched_barrier(0);
    __builtin_amdgcn_s_barrier();
    __builtin_amdgcn_sched_barrier(0);
    cur = (cur + 1 == 3) ? 0 : cur + 1;
  }
  COMPUTE(cur);
  asm volatile("s_waitcnt vmcnt(0)" ::: "memory");
  __builtin_amdgcn_sched_barrier(0);
  __builtin_amdgcn_s_barrier();
  __builtin_amdgcn_sched_barrier(0);
  cur = (cur + 1 == 3) ? 0 : cur + 1;
  COMPUTE(cur);

#pragma unroll
  for (int mi = 0; mi < 4; ++mi) {
#pragma unroll
    for (int ni = 0; ni < 4; ++ni) {
      const int gc = c0 + wc*64 + ni*16 + lr;
      const float bias = pb[gc];
#pragma unroll
      for (int r = 0; r < 4; ++r) {
        const int tok = n0 + wr*64 + mi*16 + lk*4 + r;
        if (tok < N_)
          out[((long)b*N_ + tok)*768 + gc] = acc[mi][ni][r] + bias;
      }
    }
  }
}

extern "C" void kernel_launch(void* const* d_in, const int* in_sizes, int n_in,
                              void* d_out, int out_size, void* d_ws, size_t ws_size,
                              hipStream_t stream) {
  const float* x      = (const float*)d_in[0];
  const float* rope   = (const float*)d_in[1];
  const float* qkv_w  = (const float*)d_in[2];
  const float* q_bias = (const float*)d_in[3];
  const float* v_bias = (const float*)d_in[4];
  const float* proj_w = (const float*)d_in[5];
  const float* proj_b = (const float*)d_in[6];
  float* out = (float*)d_out;

  char* w0 = (char*)d_ws;
  unsigned short* x_bf  = (unsigned short*)w0;
  unsigned short* wq_bf = (unsigned short*)(w0 + 50343936);
  unsigned short* qkv   = (unsigned short*)(w0 + 50343936 + 3538944);
  float*          part  = (float*)w0;                     // aliases x_bf (dead)
  float*          kvf   = (float*)(w0 + 25165824);
  unsigned short* McT   = (unsigned short*)(w0 + 25165824 + 1572864);

  cvt_kernel<<<2048, 256, 0, stream>>>(x, x_bf, (long)M_TOT*768/4);
  cvt_kernel<<<1728, 256, 0, stream>>>(qkv_w, wq_bf, (long)K3*768/4);

  gemm_qkv_rope<<<1161, 512, 0, stream>>>(x_bf, wq_bf, rope, q_bias, v_bias, qkv);

  kv_partial_kernel<<<dim3(CHUNKS, 96), 256, 0, stream>>>(qkv, part);
  kv_reduce_kernel<<<1536, 256, 0, stream>>>(part, kvf);
  mcomb_kernel<<<768, 256, 0, stream>>>(kvf, proj_w, McT);

  gemm_final<<<1584, 256, 0, stream>>>(qkv, McT, proj_b, out);
}

// Round 5
// 569.513 us; speedup vs baseline: 1.1697x; 1.1462x over previous
//
#include <hip/hip_runtime.h>
#include <hip/hip_bf16.h>

typedef __attribute__((ext_vector_type(8))) short short8;
typedef __attribute__((ext_vector_type(4))) float f32x4;

#define B_    8
#define N_    4097
#define C_    768
#define M_TOT (B_*N_)      /* 32776 */
#define K3    (3*C_)       /* 2304  */
#define CHUNKS 16
#define NSTEP 24           /* 768/32 K-steps */

__device__ __forceinline__ float bf2f(unsigned short u) {
  union { unsigned int i; float f; } x; x.i = ((unsigned int)u) << 16; return x.f;
}
__device__ __forceinline__ unsigned short f2bf(float f) {
  union { float f; unsigned int i; } x; x.f = f;
  unsigned int i = x.i + 0x7fffu + ((x.i >> 16) & 1u);
  return (unsigned short)(i >> 16);
}
__device__ __forceinline__ void gload16(const void* g, void* l) {
  __builtin_amdgcn_global_load_lds(
      (const __attribute__((address_space(1))) void*)g,
      (__attribute__((address_space(3))) void*)l, 16, 0, 0);
}

// ---------------- fp32 -> bf16 convert (x then qkv_w, one kernel) ----------------
__global__ __launch_bounds__(256) void cvt_kernel(const float* __restrict__ inx,
                                                  unsigned short* __restrict__ outx,
                                                  const float* __restrict__ inw,
                                                  unsigned short* __restrict__ outw,
                                                  long n4x, long n4tot) {
  long i = (long)blockIdx.x * blockDim.x + threadIdx.x;
  long stride = (long)gridDim.x * blockDim.x;
  for (; i < n4tot; i += stride) {
    const float4* src; ushort4* dst; long j;
    if (i < n4x) { src = (const float4*)inx; dst = (ushort4*)outx; j = i; }
    else         { src = (const float4*)inw; dst = (ushort4*)outw; j = i - n4x; }
    float4 v = src[j];
    ushort4 o;
    o.x = f2bf(v.x); o.y = f2bf(v.y); o.z = f2bf(v.z); o.w = f2bf(v.w);
    dst[j] = o;
  }
}

// ============ GEMM1: qkv = x @ qkv_w^T  (128x256 tile, ring-3 BK=32, R2 schedule) ============
// slot layout: [0,8K) A(128x32), [8K,24K) B(256x32). 3 slots = 72KB -> 2 blocks/CU.
__global__ __launch_bounds__(512, 4) void gemm_qkv_rope(
    const unsigned short* __restrict__ A,    // [32776,768]
    const unsigned short* __restrict__ Bw,   // [2304,768]
    const float* __restrict__ rope,          // [4096,128]
    const float* __restrict__ qb,
    const float* __restrict__ vb,
    unsigned short* __restrict__ qkv)        // planes [3][32776][768]
{
  __shared__ __align__(16) char L[3*24576];
  const int tid  = threadIdx.x;
  const int wave = tid >> 6, lane = tid & 63;
  const int lr = lane & 15, lk = lane >> 4;
  const int wm = wave >> 2, wn = wave & 3;   // 2 x 4 wave grid, each 64x64 out

  // bijective XCD swizzle: nwg = 257*9 = 2313, q=289, r=1
  const int o = blockIdx.x;
  const int xcd = o & 7, loc = o >> 3;
  const int tile = (xcd < 1 ? xcd*290 : 290 + (xcd-1)*289) + loc;
  const int m0 = (tile / 9) * 128;           // n-fastest: A-panel reuse, B L2-resident
  const int n0 = (tile % 9) * 256;

  // ---- staging addresses: thread covers one A 16B-chunk + two B 16B-chunks ----
  const int arow = tid >> 2, achk = tid & 3;
  const int am = min(m0 + arow, M_TOT-1);
  const unsigned short* gA  = A  + (long)am*768 + achk*8;
  const unsigned short* gB1 = Bw + (long)(n0 + arow)*768 + achk*8;
  const unsigned short* gB2 = Bw + (long)(n0 + arow + 128)*768 + achk*8;
  const int dA  = wave*1024;                 // + lane*16 implicit
  const int dB1 = 8192  + wave*1024;
  const int dB2 = 16384 + wave*1024;

  const int abase = (wm*64 + lr)*64 + lk*16;          // byte offsets in slot
  const int bbase = 8192 + (wn*64 + lr)*64 + lk*16;

  f32x4 acc[4][4];
#pragma unroll
  for (int i = 0; i < 4; ++i)
#pragma unroll
    for (int j = 0; j < 4; ++j) acc[i][j] = (f32x4){0.f,0.f,0.f,0.f};

  auto STAGE = [&](int buf, int kk) {
    char* sb = L + buf*24576;
    gload16(gA  + kk, sb + dA);
    gload16(gB1 + kk, sb + dB1);
    gload16(gB2 + kk, sb + dB2);
  };
  auto COMPUTE = [&](int buf) {
    const char* sb = L + buf*24576;
    short8 af[4], bfr[4];
#pragma unroll
    for (int mi = 0; mi < 4; ++mi)
      af[mi] = *(const short8*)(sb + abase + mi*1024);
#pragma unroll
    for (int ni = 0; ni < 4; ++ni)
      bfr[ni] = *(const short8*)(sb + bbase + ni*1024);
#pragma unroll
    for (int mi = 0; mi < 4; ++mi)
#pragma unroll
      for (int ni = 0; ni < 4; ++ni)
        acc[mi][ni] = __builtin_amdgcn_mfma_f32_16x16x32_bf16(af[mi], bfr[ni], acc[mi][ni], 0, 0, 0);
  };

  STAGE(0, 0);
  STAGE(1, 32);
  asm volatile("s_waitcnt vmcnt(3)" ::: "memory");   // slot 0 landed; slot 1 in flight
  __builtin_amdgcn_s_barrier();
  __builtin_amdgcn_sched_barrier(0);

  int cur = 0;
  for (int tt = 0; tt < NSTEP-2; ++tt) {
    int stg = cur + 2; if (stg >= 3) stg -= 3;
    STAGE(stg, (tt+2)*32);
    COMPUTE(cur);
    asm volatile("s_waitcnt vmcnt(3)" ::: "memory"); // slot tt+1 landed; tt+2 in flight
    __builtin_amdgcn_sched_barrier(0);
    __builtin_amdgcn_s_barrier();
    __builtin_amdgcn_sched_barrier(0);
    cur = (cur + 1 == 3) ? 0 : cur + 1;
  }
  COMPUTE(cur);                                      // step NSTEP-2
  asm volatile("s_waitcnt vmcnt(0)" ::: "memory");
  __builtin_amdgcn_sched_barrier(0);
  __builtin_amdgcn_s_barrier();
  __builtin_amdgcn_sched_barrier(0);
  cur = (cur + 1 == 3) ? 0 : cur + 1;
  COMPUTE(cur);                                      // step NSTEP-1

  // ---- epilogue: bias + RoPE + bf16 store to planes ----
  const int which = n0 / 768;                        // block-uniform (768 % 256 == 0)
  unsigned short* plane = qkv + (long)which*M_TOT*768;
#pragma unroll
  for (int mi = 0; mi < 4; ++mi) {
#pragma unroll
    for (int ni = 0; ni < 4; ++ni) {
      const int gc = n0 + wn*64 + ni*16 + lr;
      const int within = gc - which*768;
      const int d = within & 63;
      float bias = 0.f;
      if (which == 0) bias = qb[within];
      else if (which == 2) bias = vb[within];
#pragma unroll
      for (int r = 0; r < 4; ++r) {
        const int gm = m0 + wm*64 + mi*16 + lk*4 + r;
        float v = acc[mi][ni][r] + bias;
        float pair = __shfl_xor(v, 1);               // col d^1 lives in lane^1
        float vo = v;
        if (which < 2) {
          const int ntok = gm % 4097;
          if (ntok > 0 && gm < M_TOT) {
            const float* rp = rope + (long)(ntok - 1)*128 + d;
            const float s = rp[0], c = rp[64];
            const float rot = (d & 1) ? pair : -pair;
            vo = v*c + rot*s;
          }
        }
        if (gm < M_TOT) plane[(long)gm*768 + within] = f2bf(vo);
      }
    }
  }
}

// ---------------- kv partials: kv[b,h] = K^T V over an N-chunk ----------------
__global__ __launch_bounds__(256) void kv_partial_kernel(
    const unsigned short* __restrict__ qkv, float* __restrict__ part)
{
  const int bh = blockIdx.y;
  const int b = bh / 12, h = bh % 12;
  const int chunk = blockIdx.x;
  const int per = (N_ + CHUNKS - 1) / CHUNKS;
  const int nst = chunk * per;
  const int nen = min(nst + per, N_);
  const unsigned short* Kpl = qkv + (long)M_TOT*768 + ((long)b*N_)*768 + h*64;
  const unsigned short* Vpl = qkv + (long)2*M_TOT*768 + ((long)b*N_)*768 + h*64;
  __shared__ unsigned short Kl[32*64];
  __shared__ unsigned short Vl[32*64];
  const int t = threadIdx.x;
  const int ty = t >> 4, tx = t & 15;
  const int lrow = t >> 3, lpc = t & 7;
  float acc[4][4] = {};
  for (int nb = nst; nb < nen; nb += 32) {
    const int cnt = min(32, nen - nb);
    __syncthreads();
    if (lrow < cnt) {
      *(uint4*)(Kl + lrow*64 + lpc*8) = *(const uint4*)(Kpl + (long)(nb + lrow)*768 + lpc*8);
      *(uint4*)(Vl + lrow*64 + lpc*8) = *(const uint4*)(Vpl + (long)(nb + lrow)*768 + lpc*8);
    }
    __syncthreads();
#pragma unroll 2
    for (int i = 0; i < cnt; ++i) {
      const ushort4 ku = *(const ushort4*)(Kl + i*64 + ty*4);
      const ushort4 vu = *(const ushort4*)(Vl + i*64 + tx*4);
      float kf[4] = {bf2f(ku.x), bf2f(ku.y), bf2f(ku.z), bf2f(ku.w)};
      float vf[4] = {bf2f(vu.x), bf2f(vu.y), bf2f(vu.z), bf2f(vu.w)};
#pragma unroll
      for (int a = 0; a < 4; ++a)
#pragma unroll
        for (int e = 0; e < 4; ++e) acc[a][e] += kf[a]*vf[e];
    }
  }
  float* dst = part + ((long)chunk*96 + bh)*4096 + (ty*4)*64 + tx*4;
#pragma unroll
  for (int a = 0; a < 4; ++a)
#pragma unroll
    for (int e = 0; e < 4; ++e) dst[a*64 + e] = acc[a][e];
}

// ---- McombT[b][c][h*64+d] = sum_e kv[b,h,d,e]*proj_w[c,h*64+e] / (hd*N) ----
// reads 16-chunk partials directly (kv_reduce folded in).
__global__ __launch_bounds__(256) void mcomb_kernel(const float* __restrict__ part,
                                                    const float* __restrict__ pw,
                                                    unsigned short* __restrict__ McT) {
  const int blk = blockIdx.x;
  const int dg = blk & 7;
  const int h  = (blk >> 3) % 12;
  const int b  = blk / 96;
  const int bh = b*12 + h;
  __shared__ float kvs[8][64];
  const int t = threadIdx.x;
  if (t < 128) {
    const int d = t >> 4, e4 = t & 15;
    float4 s = {0.f,0.f,0.f,0.f};
    const float4* p4 = (const float4*)part;
#pragma unroll
    for (int c = 0; c < CHUNKS; ++c) {
      float4 v = p4[((long)c*96 + bh)*1024 + (dg*8 + d)*16 + e4];
      s.x += v.x; s.y += v.y; s.z += v.z; s.w += v.w;
    }
    ((float4*)kvs[d])[e4] = s;
  }
  __syncthreads();
  const float scale = (float)(1.0/(64.0*4097.0));
#pragma unroll
  for (int ci = 0; ci < 3; ++ci) {
    const int c = t + ci*256;
    const float4* pwp = (const float4*)(pw + (long)c*768 + h*64);
    float4 pv[16];
#pragma unroll
    for (int i = 0; i < 16; ++i) pv[i] = pwp[i];
#pragma unroll
    for (int d = 0; d < 8; ++d) {
      float s = 0.f;
#pragma unroll
      for (int e4 = 0; e4 < 16; ++e4) {
        const float4 kq = ((const float4*)kvs[d])[e4];
        s += pv[e4].x*kq.x + pv[e4].y*kq.y + pv[e4].z*kq.z + pv[e4].w*kq.w;
      }
      McT[((long)b*768 + c)*768 + h*64 + dg*8 + d] = f2bf(s * scale);
    }
  }
}

// ============ GEMM2: out[b] = Q[b] @ McT[b]^T + proj_b (128x256 tile, ring-3) ============
__global__ __launch_bounds__(512, 4) void gemm_final(
    const unsigned short* __restrict__ qkv,   // q plane = first M_TOT*768
    const unsigned short* __restrict__ McT,   // [8,768,768] bf16
    const float* __restrict__ pb,
    float* __restrict__ out)
{
  __shared__ __align__(16) char L[3*24576];
  const int tid  = threadIdx.x;
  const int wave = tid >> 6, lane = tid & 63;
  const int lr = lane & 15, lk = lane >> 4;
  const int wm = wave >> 2, wn = wave & 3;

  // XCD swizzle: nwg = 8*33*3 = 792 = 8*99 (one batch per XCD)
  const int o = blockIdx.x;
  const int xcd = o & 7, loc = o >> 3;
  const int b  = xcd;
  const int mt = loc / 3, ct = loc % 3;      // ct-fastest: A-panel reuse over 3 tiles
  const int m0 = mt * 128;
  const int c0 = ct * 256;

  const int arow = tid >> 2, achk = tid & 3;
  const int am = min(m0 + arow, N_-1);
  const unsigned short* gA  = qkv + ((long)b*N_ + am)*768 + achk*8;
  const unsigned short* Bb  = McT + (long)b*768*768;
  const unsigned short* gB1 = Bb + (long)(c0 + arow)*768 + achk*8;
  const unsigned short* gB2 = Bb + (long)(c0 + arow + 128)*768 + achk*8;
  const int dA  = wave*1024;
  const int dB1 = 8192  + wave*1024;
  const int dB2 = 16384 + wave*1024;

  const int abase = (wm*64 + lr)*64 + lk*16;
  const int bbase = 8192 + (wn*64 + lr)*64 + lk*16;

  f32x4 acc[4][4];
#pragma unroll
  for (int i = 0; i < 4; ++i)
#pragma unroll
    for (int j = 0; j < 4; ++j) acc[i][j] = (f32x4){0.f,0.f,0.f,0.f};

  auto STAGE = [&](int buf, int kk) {
    char* sb = L + buf*24576;
    gload16(gA  + kk, sb + dA);
    gload16(gB1 + kk, sb + dB1);
    gload16(gB2 + kk, sb + dB2);
  };
  auto COMPUTE = [&](int buf) {
    const char* sb = L + buf*24576;
    short8 af[4], bfr[4];
#pragma unroll
    for (int mi = 0; mi < 4; ++mi)
      af[mi] = *(const short8*)(sb + abase + mi*1024);
#pragma unroll
    for (int ni = 0; ni < 4; ++ni)
      bfr[ni] = *(const short8*)(sb + bbase + ni*1024);
#pragma unroll
    for (int mi = 0; mi < 4; ++mi)
#pragma unroll
      for (int ni = 0; ni < 4; ++ni)
        acc[mi][ni] = __builtin_amdgcn_mfma_f32_16x16x32_bf16(af[mi], bfr[ni], acc[mi][ni], 0, 0, 0);
  };

  STAGE(0, 0);
  STAGE(1, 32);
  asm volatile("s_waitcnt vmcnt(3)" ::: "memory");
  __builtin_amdgcn_s_barrier();
  __builtin_amdgcn_sched_barrier(0);

  int cur = 0;
  for (int tt = 0; tt < NSTEP-2; ++tt) {
    int stg = cur + 2; if (stg >= 3) stg -= 3;
    STAGE(stg, (tt+2)*32);
    COMPUTE(cur);
    asm volatile("s_waitcnt vmcnt(3)" ::: "memory");
    __builtin_amdgcn_sched_barrier(0);
    __builtin_amdgcn_s_barrier();
    __builtin_amdgcn_sched_barrier(0);
    cur = (cur + 1 == 3) ? 0 : cur + 1;
  }
  COMPUTE(cur);
  asm volatile("s_waitcnt vmcnt(0)" ::: "memory");
  __builtin_amdgcn_sched_barrier(0);
  __builtin_amdgcn_s_barrier();
  __builtin_amdgcn_sched_barrier(0);
  cur = (cur + 1 == 3) ? 0 : cur + 1;
  COMPUTE(cur);

#pragma unroll
  for (int mi = 0; mi < 4; ++mi) {
#pragma unroll
    for (int ni = 0; ni < 4; ++ni) {
      const int gc = c0 + wn*64 + ni*16 + lr;
      const float bias = pb[gc];
#pragma unroll
      for (int r = 0; r < 4; ++r) {
        const int tok = m0 + wm*64 + mi*16 + lk*4 + r;
        if (tok < N_)
          out[((long)b*N_ + tok)*768 + gc] = acc[mi][ni][r] + bias;
      }
    }
  }
}

extern "C" void kernel_launch(void* const* d_in, const int* in_sizes, int n_in,
                              void* d_out, int out_size, void* d_ws, size_t ws_size,
                              hipStream_t stream) {
  const float* x      = (const float*)d_in[0];
  const float* rope   = (const float*)d_in[1];
  const float* qkv_w  = (const float*)d_in[2];
  const float* q_bias = (const float*)d_in[3];
  const float* v_bias = (const float*)d_in[4];
  const float* proj_w = (const float*)d_in[5];
  const float* proj_b = (const float*)d_in[6];
  float* out = (float*)d_out;

  char* w0 = (char*)d_ws;
  unsigned short* x_bf  = (unsigned short*)w0;                        // dead after gemm1
  unsigned short* wq_bf = (unsigned short*)(w0 + 50343936);
  unsigned short* qkv   = (unsigned short*)(w0 + 50343936 + 3538944);
  float*          part  = (float*)w0;                                 // aliases x_bf
  unsigned short* McT   = (unsigned short*)(w0 + 25165824 + 1572864);

  const long n4x = (long)M_TOT*768/4;
  const long n4w = (long)K3*768/4;
  cvt_kernel<<<2048, 256, 0, stream>>>(x, x_bf, qkv_w, wq_bf, n4x, n4x + n4w);

  gemm_qkv_rope<<<2313, 512, 0, stream>>>(x_bf, wq_bf, rope, q_bias, v_bias, qkv);

  kv_partial_kernel<<<dim3(CHUNKS, 96), 256, 0, stream>>>(qkv, part);
  mcomb_kernel<<<768, 256, 0, stream>>>(part, proj_w, McT);

  gemm_final<<<792, 512, 0, stream>>>(qkv, McT, proj_b, out);
}

// Round 6
// 434.489 us; speedup vs baseline: 1.5332x; 1.3108x over previous
//
#include <hip/hip_runtime.h>
#include <hip/hip_bf16.h>

typedef __attribute__((ext_vector_type(8))) short short8;
typedef __attribute__((ext_vector_type(4))) float f32x4;

#define B_    8
#define N_    4097
#define C_    768
#define M_TOT (B_*N_)      /* 32776 */
#define K3    (3*C_)       /* 2304  */
#define CHUNKS 16
#define NSTEP 24           /* 768/32 K-steps */

__device__ __forceinline__ float bf2f(unsigned short u) {
  union { unsigned int i; float f; } x; x.i = ((unsigned int)u) << 16; return x.f;
}
__device__ __forceinline__ unsigned short f2bf(float f) {
  union { float f; unsigned int i; } x; x.f = f;
  unsigned int i = x.i + 0x7fffu + ((x.i >> 16) & 1u);
  return (unsigned short)(i >> 16);
}
__device__ __forceinline__ void gload16(const void* g, void* l) {
  __builtin_amdgcn_global_load_lds(
      (const __attribute__((address_space(1))) void*)g,
      (__attribute__((address_space(3))) void*)l, 16, 0, 0);
}

// ---------------- fp32 -> bf16 convert (x then qkv_w, one kernel) ----------------
__global__ __launch_bounds__(256) void cvt_kernel(const float* __restrict__ inx,
                                                  unsigned short* __restrict__ outx,
                                                  const float* __restrict__ inw,
                                                  unsigned short* __restrict__ outw,
                                                  long n4x, long n4tot) {
  long i = (long)blockIdx.x * blockDim.x + threadIdx.x;
  long stride = (long)gridDim.x * blockDim.x;
  for (; i < n4tot; i += stride) {
    const float4* src; ushort4* dst; long j;
    if (i < n4x) { src = (const float4*)inx; dst = (ushort4*)outx; j = i; }
    else         { src = (const float4*)inw; dst = (ushort4*)outw; j = i - n4x; }
    float4 v = src[j];
    ushort4 o;
    o.x = f2bf(v.x); o.y = f2bf(v.y); o.z = f2bf(v.z); o.w = f2bf(v.w);
    dst[j] = o;
  }
}

// ============ GEMM1: qkv = x @ qkv_w^T  (128x256 tile, ring-3 BK=32) ============
__global__ __launch_bounds__(512, 4) void gemm_qkv_rope(
    const unsigned short* __restrict__ A,    // [32776,768]
    const unsigned short* __restrict__ Bw,   // [2304,768]
    const float* __restrict__ rope,          // [4096,128]
    const float* __restrict__ qb,
    const float* __restrict__ vb,
    unsigned short* __restrict__ qkv)        // planes [3][32776][768]
{
  __shared__ __align__(16) char L[3*24576];
  const int tid  = threadIdx.x;
  const int wave = tid >> 6, lane = tid & 63;
  const int lr = lane & 15, lk = lane >> 4;
  const int wm = wave >> 2, wn = wave & 3;

  // bijective XCD swizzle: nwg = 257*9 = 2313, q=289, r=1
  const int o = blockIdx.x;
  const int xcd = o & 7, loc = o >> 3;
  const int tile = (xcd < 1 ? xcd*290 : 290 + (xcd-1)*289) + loc;
  const int m0 = (tile / 9) * 128;
  const int n0 = (tile % 9) * 256;

  const int arow = tid >> 2, achk = tid & 3;
  const int am = min(m0 + arow, M_TOT-1);
  const unsigned short* gA  = A  + (long)am*768 + achk*8;
  const unsigned short* gB1 = Bw + (long)(n0 + arow)*768 + achk*8;
  const unsigned short* gB2 = Bw + (long)(n0 + arow + 128)*768 + achk*8;
  const int dA  = wave*1024;
  const int dB1 = 8192  + wave*1024;
  const int dB2 = 16384 + wave*1024;

  const int abase = (wm*64 + lr)*64 + lk*16;
  const int bbase = 8192 + (wn*64 + lr)*64 + lk*16;

  f32x4 acc[4][4];
#pragma unroll
  for (int i = 0; i < 4; ++i)
#pragma unroll
    for (int j = 0; j < 4; ++j) acc[i][j] = (f32x4){0.f,0.f,0.f,0.f};

  auto STAGE = [&](int buf, int kk) {
    char* sb = L + buf*24576;
    gload16(gA  + kk, sb + dA);
    gload16(gB1 + kk, sb + dB1);
    gload16(gB2 + kk, sb + dB2);
  };
  auto COMPUTE = [&](int buf) {
    const char* sb = L + buf*24576;
    short8 af[4], bfr[4];
#pragma unroll
    for (int mi = 0; mi < 4; ++mi)
      af[mi] = *(const short8*)(sb + abase + mi*1024);
#pragma unroll
    for (int ni = 0; ni < 4; ++ni)
      bfr[ni] = *(const short8*)(sb + bbase + ni*1024);
#pragma unroll
    for (int mi = 0; mi < 4; ++mi)
#pragma unroll
      for (int ni = 0; ni < 4; ++ni)
        acc[mi][ni] = __builtin_amdgcn_mfma_f32_16x16x32_bf16(af[mi], bfr[ni], acc[mi][ni], 0, 0, 0);
  };

  STAGE(0, 0);
  STAGE(1, 32);
  asm volatile("s_waitcnt vmcnt(3)" ::: "memory");
  __builtin_amdgcn_s_barrier();
  __builtin_amdgcn_sched_barrier(0);

  int cur = 0;
  for (int tt = 0; tt < NSTEP-2; ++tt) {
    int stg = cur + 2; if (stg >= 3) stg -= 3;
    STAGE(stg, (tt+2)*32);
    COMPUTE(cur);
    asm volatile("s_waitcnt vmcnt(3)" ::: "memory");
    __builtin_amdgcn_sched_barrier(0);
    __builtin_amdgcn_s_barrier();
    __builtin_amdgcn_sched_barrier(0);
    cur = (cur + 1 == 3) ? 0 : cur + 1;
  }
  COMPUTE(cur);
  asm volatile("s_waitcnt vmcnt(0)" ::: "memory");
  __builtin_amdgcn_sched_barrier(0);
  __builtin_amdgcn_s_barrier();
  __builtin_amdgcn_sched_barrier(0);
  cur = (cur + 1 == 3) ? 0 : cur + 1;
  COMPUTE(cur);

  const int which = n0 / 768;
  unsigned short* plane = qkv + (long)which*M_TOT*768;
#pragma unroll
  for (int mi = 0; mi < 4; ++mi) {
#pragma unroll
    for (int ni = 0; ni < 4; ++ni) {
      const int gc = n0 + wn*64 + ni*16 + lr;
      const int within = gc - which*768;
      const int d = within & 63;
      float bias = 0.f;
      if (which == 0) bias = qb[within];
      else if (which == 2) bias = vb[within];
#pragma unroll
      for (int r = 0; r < 4; ++r) {
        const int gm = m0 + wm*64 + mi*16 + lk*4 + r;
        float v = acc[mi][ni][r] + bias;
        float pair = __shfl_xor(v, 1);
        float vo = v;
        if (which < 2) {
          const int ntok = gm % 4097;
          if (ntok > 0 && gm < M_TOT) {
            const float* rp = rope + (long)(ntok - 1)*128 + d;
            const float s = rp[0], c = rp[64];
            const float rot = (d & 1) ? pair : -pair;
            vo = v*c + rot*s;
          }
        }
        if (gm < M_TOT) plane[(long)gm*768 + within] = f2bf(vo);
      }
    }
  }
}

// ---------------- kv partials: kv[b,h] = K^T V over an N-chunk ----------------
__global__ __launch_bounds__(256) void kv_partial_kernel(
    const unsigned short* __restrict__ qkv, float* __restrict__ part)
{
  const int bh = blockIdx.y;
  const int b = bh / 12, h = bh % 12;
  const int chunk = blockIdx.x;
  const int per = (N_ + CHUNKS - 1) / CHUNKS;
  const int nst = chunk * per;
  const int nen = min(nst + per, N_);
  const unsigned short* Kpl = qkv + (long)M_TOT*768 + ((long)b*N_)*768 + h*64;
  const unsigned short* Vpl = qkv + (long)2*M_TOT*768 + ((long)b*N_)*768 + h*64;
  __shared__ unsigned short Kl[32*64];
  __shared__ unsigned short Vl[32*64];
  const int t = threadIdx.x;
  const int ty = t >> 4, tx = t & 15;
  const int lrow = t >> 3, lpc = t & 7;
  float acc[4][4] = {};
  for (int nb = nst; nb < nen; nb += 32) {
    const int cnt = min(32, nen - nb);
    __syncthreads();
    if (lrow < cnt) {
      *(uint4*)(Kl + lrow*64 + lpc*8) = *(const uint4*)(Kpl + (long)(nb + lrow)*768 + lpc*8);
      *(uint4*)(Vl + lrow*64 + lpc*8) = *(const uint4*)(Vpl + (long)(nb + lrow)*768 + lpc*8);
    }
    __syncthreads();
#pragma unroll 2
    for (int i = 0; i < cnt; ++i) {
      const ushort4 ku = *(const ushort4*)(Kl + i*64 + ty*4);
      const ushort4 vu = *(const ushort4*)(Vl + i*64 + tx*4);
      float kf[4] = {bf2f(ku.x), bf2f(ku.y), bf2f(ku.z), bf2f(ku.w)};
      float vf[4] = {bf2f(vu.x), bf2f(vu.y), bf2f(vu.z), bf2f(vu.w)};
#pragma unroll
      for (int a = 0; a < 4; ++a)
#pragma unroll
        for (int e = 0; e < 4; ++e) acc[a][e] += kf[a]*vf[e];
    }
  }
  float* dst = part + ((long)chunk*96 + bh)*4096 + (ty*4)*64 + tx*4;
#pragma unroll
  for (int a = 0; a < 4; ++a)
#pragma unroll
    for (int e = 0; e < 4; ++e) dst[a*64 + e] = acc[a][e];
}

// ---- McombT[b][c][h*64+d] = sum_e kv[b,h,d,e]*pw[c,h*64+e] / (hd*N) ----
// block = (cs, h, b); lane d owns one output column slice; pw rows go through
// the SCALAR path (wave-uniform address -> s_load + v_fmac w/ SGPR operand).
__global__ __launch_bounds__(256) void mcomb_kernel(const float* __restrict__ part,
                                                    const float* __restrict__ pw,
                                                    unsigned short* __restrict__ McT) {
  const int blk = blockIdx.x;            // 8*12*2 = 192
  const int cs = blk & 1;
  const int h  = (blk >> 1) % 12;
  const int b  = blk / 24;
  const int bh = b*12 + h;
  __shared__ float kvs[64][65];          // kvs[e][d]
  const int t = threadIdx.x;
  const int d_own = t >> 2;              // 0..63
  const int eg = (t & 3) * 16;           // e-group base (16 e per group)

  // accumulate 16 chunks of part[d][e] into registers (coalesced float4 reads)
  float4 a0 = {0,0,0,0}, a1 = {0,0,0,0}, a2 = {0,0,0,0}, a3 = {0,0,0,0};
  const float4* p4 = (const float4*)part;
#pragma unroll
  for (int ch = 0; ch < CHUNKS; ++ch) {
    const long base = ((long)ch*96 + bh)*1024 + d_own*16 + (t & 3)*4;
    float4 v0 = p4[base+0], v1 = p4[base+1], v2 = p4[base+2], v3 = p4[base+3];
    a0.x += v0.x; a0.y += v0.y; a0.z += v0.z; a0.w += v0.w;
    a1.x += v1.x; a1.y += v1.y; a1.z += v1.z; a1.w += v1.w;
    a2.x += v2.x; a2.y += v2.y; a2.z += v2.z; a2.w += v2.w;
    a3.x += v3.x; a3.y += v3.y; a3.z += v3.z; a3.w += v3.w;
  }
  // transpose into LDS: kvs[e][d]
  kvs[eg+ 0][d_own] = a0.x; kvs[eg+ 1][d_own] = a0.y; kvs[eg+ 2][d_own] = a0.z; kvs[eg+ 3][d_own] = a0.w;
  kvs[eg+ 4][d_own] = a1.x; kvs[eg+ 5][d_own] = a1.y; kvs[eg+ 6][d_own] = a1.z; kvs[eg+ 7][d_own] = a1.w;
  kvs[eg+ 8][d_own] = a2.x; kvs[eg+ 9][d_own] = a2.y; kvs[eg+10][d_own] = a2.z; kvs[eg+11][d_own] = a2.w;
  kvs[eg+12][d_own] = a3.x; kvs[eg+13][d_own] = a3.y; kvs[eg+14][d_own] = a3.z; kvs[eg+15][d_own] = a3.w;
  __syncthreads();

  const int lane = t & 63;               // = d
  const int w    = t >> 6;               // wave 0..3
  float kvcol[64];
#pragma unroll
  for (int e = 0; e < 64; ++e) kvcol[e] = kvs[e][lane];

  const float scale = (float)(1.0/(64.0*4097.0));
  const int cbase = cs*384 + w*96;
  for (int i = 0; i < 96; ++i) {
    const int c = cbase + i;             // wave-uniform
    const float* pwrow = pw + (long)c*768 + h*64;   // uniform address -> s_load
    float s = 0.f;
#pragma unroll
    for (int e = 0; e < 64; ++e) s += pwrow[e] * kvcol[e];
    McT[((long)b*768 + c)*768 + h*64 + lane] = f2bf(s * scale);
  }
}

// ============ GEMM2: out[b] = Q[b] @ McT[b]^T + proj_b (128x256 tile, ring-3) ============
__global__ __launch_bounds__(512, 4) void gemm_final(
    const unsigned short* __restrict__ qkv,   // q plane = first M_TOT*768
    const unsigned short* __restrict__ McT,   // [8,768,768] bf16
    const float* __restrict__ pb,
    float* __restrict__ out)
{
  __shared__ __align__(16) char L[3*24576];
  const int tid  = threadIdx.x;
  const int wave = tid >> 6, lane = tid & 63;
  const int lr = lane & 15, lk = lane >> 4;
  const int wm = wave >> 2, wn = wave & 3;

  // XCD swizzle: nwg = 8*33*3 = 792 (one batch per XCD)
  const int o = blockIdx.x;
  const int xcd = o & 7, loc = o >> 3;
  const int b  = xcd;
  const int mt = loc / 3, ct = loc % 3;
  const int m0 = mt * 128;
  const int c0 = ct * 256;

  const int arow = tid >> 2, achk = tid & 3;
  const int am = min(m0 + arow, N_-1);
  const unsigned short* gA  = qkv + ((long)b*N_ + am)*768 + achk*8;
  const unsigned short* Bb  = McT + (long)b*768*768;
  const unsigned short* gB1 = Bb + (long)(c0 + arow)*768 + achk*8;
  const unsigned short* gB2 = Bb + (long)(c0 + arow + 128)*768 + achk*8;
  const int dA  = wave*1024;
  const int dB1 = 8192  + wave*1024;
  const int dB2 = 16384 + wave*1024;

  const int abase = (wm*64 + lr)*64 + lk*16;
  const int bbase = 8192 + (wn*64 + lr)*64 + lk*16;

  f32x4 acc[4][4];
#pragma unroll
  for (int i = 0; i < 4; ++i)
#pragma unroll
    for (int j = 0; j < 4; ++j) acc[i][j] = (f32x4){0.f,0.f,0.f,0.f};

  auto STAGE = [&](int buf, int kk) {
    char* sb = L + buf*24576;
    gload16(gA  + kk, sb + dA);
    gload16(gB1 + kk, sb + dB1);
    gload16(gB2 + kk, sb + dB2);
  };
  auto COMPUTE = [&](int buf) {
    const char* sb = L + buf*24576;
    short8 af[4], bfr[4];
#pragma unroll
    for (int mi = 0; mi < 4; ++mi)
      af[mi] = *(const short8*)(sb + abase + mi*1024);
#pragma unroll
    for (int ni = 0; ni < 4; ++ni)
      bfr[ni] = *(const short8*)(sb + bbase + ni*1024);
#pragma unroll
    for (int mi = 0; mi < 4; ++mi)
#pragma unroll
      for (int ni = 0; ni < 4; ++ni)
        acc[mi][ni] = __builtin_amdgcn_mfma_f32_16x16x32_bf16(af[mi], bfr[ni], acc[mi][ni], 0, 0, 0);
  };

  STAGE(0, 0);
  STAGE(1, 32);
  asm volatile("s_waitcnt vmcnt(3)" ::: "memory");
  __builtin_amdgcn_s_barrier();
  __builtin_amdgcn_sched_barrier(0);

  int cur = 0;
  for (int tt = 0; tt < NSTEP-2; ++tt) {
    int stg = cur + 2; if (stg >= 3) stg -= 3;
    STAGE(stg, (tt+2)*32);
    COMPUTE(cur);
    asm volatile("s_waitcnt vmcnt(3)" ::: "memory");
    __builtin_amdgcn_sched_barrier(0);
    __builtin_amdgcn_s_barrier();
    __builtin_amdgcn_sched_barrier(0);
    cur = (cur + 1 == 3) ? 0 : cur + 1;
  }
  COMPUTE(cur);
  asm volatile("s_waitcnt vmcnt(0)" ::: "memory");
  __builtin_amdgcn_sched_barrier(0);
  __builtin_amdgcn_s_barrier();
  __builtin_amdgcn_sched_barrier(0);
  cur = (cur + 1 == 3) ? 0 : cur + 1;
  COMPUTE(cur);

#pragma unroll
  for (int mi = 0; mi < 4; ++mi) {
#pragma unroll
    for (int ni = 0; ni < 4; ++ni) {
      const int gc = c0 + wn*64 + ni*16 + lr;
      const float bias = pb[gc];
#pragma unroll
      for (int r = 0; r < 4; ++r) {
        const int tok = m0 + wm*64 + mi*16 + lk*4 + r;
        if (tok < N_)
          out[((long)b*N_ + tok)*768 + gc] = acc[mi][ni][r] + bias;
      }
    }
  }
}

extern "C" void kernel_launch(void* const* d_in, const int* in_sizes, int n_in,
                              void* d_out, int out_size, void* d_ws, size_t ws_size,
                              hipStream_t stream) {
  const float* x      = (const float*)d_in[0];
  const float* rope   = (const float*)d_in[1];
  const float* qkv_w  = (const float*)d_in[2];
  const float* q_bias = (const float*)d_in[3];
  const float* v_bias = (const float*)d_in[4];
  const float* proj_w = (const float*)d_in[5];
  const float* proj_b = (const float*)d_in[6];
  float* out = (float*)d_out;

  char* w0 = (char*)d_ws;
  unsigned short* x_bf  = (unsigned short*)w0;                        // dead after gemm1
  unsigned short* wq_bf = (unsigned short*)(w0 + 50343936);
  unsigned short* qkv   = (unsigned short*)(w0 + 50343936 + 3538944);
  float*          part  = (float*)w0;                                 // aliases x_bf
  unsigned short* McT   = (unsigned short*)(w0 + 25165824 + 1572864);

  const long n4x = (long)M_TOT*768/4;
  const long n4w = (long)K3*768/4;
  cvt_kernel<<<2048, 256, 0, stream>>>(x, x_bf, qkv_w, wq_bf, n4x, n4x + n4w);

  gemm_qkv_rope<<<2313, 512, 0, stream>>>(x_bf, wq_bf, rope, q_bias, v_bias, qkv);

  kv_partial_kernel<<<dim3(CHUNKS, 96), 256, 0, stream>>>(qkv, part);
  mcomb_kernel<<<192, 256, 0, stream>>>(part, proj_w, McT);

  gemm_final<<<792, 512, 0, stream>>>(qkv, McT, proj_b, out);
}